// Round 12
// baseline (497.449 us; speedup 1.0000x reference)
//
#include <hip/hip_runtime.h>
#include <math.h>

// Problem dims (fixed by reference setup_inputs)
#define BH 8        // heads
#define KK 512      // clusters
#define DD 64       // dim
#define NT 16384    // tokens per head = b*n = 4*4096
#define IDS_N (NT*BH)   // 131072 cluster-id outputs
#define WAVES 8     // waves per assign block; each wave owns 64 clusters

// ws layout (u32 words):
//   [0,           4096)   g_hist  — counts per (h,k)
//   [4096,        8192)   cursor  — scan offsets, then offset+count after scatter
//   [8192, 8192+131072)   tokbuf  — token indices bucketed per (h,k)

// ---------------------------------------------------------------------------
// Kernel 1: transposed argmin. lane = cluster (wave w owns clusters
// [w*64, w*64+64), row held in 64 VGPRs pre-scaled by -2). Token loop reads
// x rows at wave-uniform addresses -> scalar s_load into SGPRs; inner loop is
// v_fmac v,s,v. Per token: 64-lane butterfly argmin, partials -> LDS,
// epilogue combines 8 waves (ascending = first-index tie rule).
// Products fl((-2m)*x) are bit-identical to the previous passing kernel's
// fl((-2x)*m); same 4-acc sum order -> dists bit-exact.
// grid = (NT/256, BH) = 512 blocks of 512 threads (2 blocks/CU).
// ---------------------------------------------------------------------------
__global__ __launch_bounds__(512, 4) void vq_assign(
    const float* __restrict__ x,       // [NT, BH*DD]
    const float* __restrict__ means,   // [BH, KK, DD]
    float* __restrict__ out_ids,       // [NT*BH]
    unsigned int* __restrict__ g_hist) // [BH*KK] pre-zeroed
{
    const int h    = blockIdx.y;
    const int tid  = threadIdx.x;
    const int w    = tid >> 6;        // wave 0..7
    const int lane = tid & 63;
    const int c    = (w << 6) + lane; // this lane's cluster 0..511

    __shared__ float pd[WAVES][256];  // per-wave best dist per token (8 KB)
    __shared__ int   pi[WAVES][256];  // per-wave best idx  per token (8 KB)
    __shared__ unsigned int s_hist[KK];

    for (int r = tid; r < KK; r += 512) s_hist[r] = 0u;

    // Prologue: this lane's cluster row -> VGPRs, scaled by -2 (exact pow2);
    // |m|^2 with the same 4-accumulator order as before.
    float row2[64];
    float m2;
    {
        const float4* mr = (const float4*)(means + ((size_t)h * KK + c) * DD);
        float a0 = 0.f, a1 = 0.f, a2 = 0.f, a3 = 0.f;
#pragma unroll
        for (int j = 0; j < 16; ++j) {
            float4 m = mr[j];
            a0 = fmaf(m.x, m.x, a0);
            a1 = fmaf(m.y, m.y, a1);
            a2 = fmaf(m.z, m.z, a2);
            a3 = fmaf(m.w, m.w, a3);
            row2[4*j+0] = -2.f * m.x;
            row2[4*j+1] = -2.f * m.y;
            row2[4*j+2] = -2.f * m.z;
            row2[4*j+3] = -2.f * m.w;
        }
        m2 = (a0 + a1) + (a2 + a3);
    }

    const float* xbase = x + (size_t)blockIdx.x * 256 * (BH * DD) + h * DD;

    for (int t = 0; t < 256; ++t) {
        const float* __restrict__ xr = xbase + (size_t)t * (BH * DD); // uniform
        float a0 = m2, a1 = 0.f, a2 = 0.f, a3 = 0.f;
#pragma unroll
        for (int j = 0; j < 16; ++j) {
            float x0 = xr[4*j+0], x1 = xr[4*j+1];
            float x2 = xr[4*j+2], x3 = xr[4*j+3];
            a0 = fmaf(x0, row2[4*j+0], a0);
            a1 = fmaf(x1, row2[4*j+1], a1);
            a2 = fmaf(x2, row2[4*j+2], a2);
            a3 = fmaf(x3, row2[4*j+3], a3);
        }
        float bd = (a0 + a1) + (a2 + a3);   // dist for (token t, cluster c)
        int   bi = c;
        // 64-lane butterfly argmin; ties -> smaller cluster index
#pragma unroll
        for (int s = 1; s < 64; s <<= 1) {
            float od = __shfl_xor(bd, s, 64);
            int   oi = __shfl_xor(bi, s, 64);
            if (od < bd || (od == bd && oi < bi)) { bd = od; bi = oi; }
        }
        if (lane == 0) { pd[w][t] = bd; pi[w][t] = bi; }
    }
    __syncthreads();

    // Epilogue: combine 8 wave-partials per token (ascending wave = ascending
    // cluster range -> first-index tie rule preserved).
    if (tid < 256) {
        float bd = pd[0][tid]; int bi = pi[0][tid];
#pragma unroll
        for (int ww = 1; ww < WAVES; ++ww) {
            float od = pd[ww][tid]; int oi = pi[ww][tid];
            if (od < bd || (od == bd && oi < bi)) { bd = od; bi = oi; }
        }
        size_t tt = (size_t)blockIdx.x * 256 + tid;
        out_ids[tt * BH + h] = (float)bi;   // [b,n,h] layout
        atomicAdd(&s_hist[bi], 1u);
    }
    __syncthreads();
    for (int r = tid; r < KK; r += 512) {
        unsigned int v = s_hist[r];
        if (v) atomicAdd(&g_hist[h * KK + r], v);
    }
}

// ---------------------------------------------------------------------------
// Kernel 2: per-head exclusive prefix sum of counts -> cursor.
// grid = BH blocks, 512 threads.
// ---------------------------------------------------------------------------
__global__ __launch_bounds__(512) void vq_scan(
    const unsigned int* __restrict__ g_hist,
    unsigned int* __restrict__ cursor)
{
    const int h = blockIdx.x;
    const int tid = threadIdx.x;
    __shared__ unsigned int s[KK];

    unsigned int own = g_hist[h * KK + tid];
    s[tid] = own;
    __syncthreads();
    for (int off = 1; off < KK; off <<= 1) {
        unsigned int v = 0;
        if (tid >= off) v = s[tid - off];
        __syncthreads();
        s[tid] += v;
        __syncthreads();
    }
    cursor[h * KK + tid] = s[tid] - own;   // exclusive
}

// ---------------------------------------------------------------------------
// Kernel 3: scatter token indices into buckets. One cursor atomic per token.
// grid = (NT/256, BH), block = 256.
// ---------------------------------------------------------------------------
__global__ __launch_bounds__(256) void vq_scatter(
    const float* __restrict__ out_ids,
    unsigned int* __restrict__ cursor,
    unsigned int* __restrict__ tokbuf)   // [BH*NT]
{
    const int h = blockIdx.y;
    const int t = blockIdx.x * 256 + threadIdx.x;
    int id = (int)out_ids[(size_t)t * BH + h];
    unsigned int slot = atomicAdd(&cursor[h * KK + id], 1u);
    tokbuf[(size_t)h * NT + slot] = (unsigned int)t;
}

// ---------------------------------------------------------------------------
// Kernel 4: one BLOCK (4 waves) per (h,k) bucket. Token dim split across
// waves, 4-deep ILP per wave (16 independent chains total). lane = dim.
// Zero atomics, fused EMA. grid = BH*KK blocks of 256.
// ---------------------------------------------------------------------------
__global__ __launch_bounds__(256) void vq_gather(
    const float* __restrict__ x,
    const float* __restrict__ means,
    const unsigned int* __restrict__ g_hist,
    const unsigned int* __restrict__ cursor,   // now offset+count
    const unsigned int* __restrict__ tokbuf,
    float* __restrict__ out_means)
{
    const int w    = blockIdx.x;            // bucket id (h*KK+k)
    const int wid  = threadIdx.x >> 6;      // wave 0..3
    const int lane = threadIdx.x & 63;
    const int h    = w >> 9;

    const unsigned int cnt = g_hist[w];
    const unsigned int off = cursor[w] - cnt;
    const unsigned int* tb = tokbuf + (size_t)h * NT + off;
    const float* xb = x + h * DD + lane;

    float a0 = 0.f, a1 = 0.f, a2 = 0.f, a3 = 0.f;
    unsigned int i = wid;
    for (; i + 12 < cnt; i += 16) {          // 4 independent loads in flight
        unsigned int t0 = tb[i], t1 = tb[i + 4], t2 = tb[i + 8], t3 = tb[i + 12];
        a0 += xb[(size_t)t0 * (BH * DD)];
        a1 += xb[(size_t)t1 * (BH * DD)];
        a2 += xb[(size_t)t2 * (BH * DD)];
        a3 += xb[(size_t)t3 * (BH * DD)];
    }
    for (; i < cnt; i += 4)
        a0 += xb[(size_t)tb[i] * (BH * DD)];

    __shared__ float sp[4][DD];
    sp[wid][lane] = (a0 + a1) + (a2 + a3);
    __syncthreads();
    if (wid == 0) {
        float s = (sp[0][lane] + sp[1][lane]) + (sp[2][lane] + sp[3][lane]);
        float nm = s / (1e-6f + (float)cnt);
        float m  = means[(size_t)w * DD + lane];
        out_means[(size_t)w * DD + lane] = 0.001f * nm + 0.999f * m;
    }
}

extern "C" void kernel_launch(void* const* d_in, const int* in_sizes, int n_in,
                              void* d_out, int out_size, void* d_ws, size_t ws_size,
                              hipStream_t stream) {
    const float* x     = (const float*)d_in[0];   // [4,4096,512] f32
    const float* means = (const float*)d_in[1];   // [8,512,64]  f32

    float* out       = (float*)d_out;
    float* out_ids   = out;            // first 131072 floats
    float* out_means = out + IDS_N;    // next 262144 floats

    unsigned int* g_hist = (unsigned int*)d_ws;          // 4096
    unsigned int* cursor = g_hist + BH * KK;             // 4096
    unsigned int* tokbuf = cursor + BH * KK;             // 131072

    hipMemsetAsync(g_hist, 0, BH * KK * sizeof(unsigned int), stream);

    dim3 agrid(NT / 256, BH);
    vq_assign <<<agrid, dim3(512), 0, stream>>>(x, means, out_ids, g_hist);
    vq_scan   <<<BH, dim3(512), 0, stream>>>(g_hist, cursor);
    dim3 sgrid(NT / 256, BH);
    vq_scatter<<<sgrid, dim3(256), 0, stream>>>(out_ids, cursor, tokbuf);
    vq_gather <<<BH * KK, dim3(256), 0, stream>>>(
        x, means, g_hist, cursor, tokbuf, out_means);
}

// Round 13
// 277.800 us; speedup vs baseline: 1.7907x; 1.7907x over previous
//
#include <hip/hip_runtime.h>
#include <math.h>

// Problem dims (fixed by reference setup_inputs)
#define BH 8        // heads
#define KK 512      // clusters
#define DD 64       // dim
#define NT 16384    // tokens per head = b*n = 4*4096
#define IDS_N (NT*BH)   // 131072 cluster-id outputs
#define CH 128      // clusters staged in LDS per chunk
#define TPB 256     // threads per assign block
#define TOK 2       // tokens per thread (amortizes broadcast ds_read)

// ws layout (u32 words):
//   [0,           4096)   g_hist  — counts per (h,k)
//   [4096,        8192)   cursor  — scan offsets, then offset+count after scatter
//   [8192, 8192+131072)   tokbuf  — token indices bucketed per (h,k)

// ---------------------------------------------------------------------------
// Kernel 1: per-token argmin, codebook staged via LDS (4 chunks x 128 rows),
// each thread owns TOK=2 tokens so every broadcast ds_read_b128 feeds 2
// tokens' FMAs (halves the LDS-return-BW bound measured at 322us in r8).
// grid = (NT/512, BH) = 256 blocks of 256 thr. Math order identical to the
// absmax=0 kernels: dist = |m|^2 + sum fl((-2x)*m), 4-acc chain, strict <.
// ---------------------------------------------------------------------------
__global__ __launch_bounds__(TPB, 2) void vq_assign(
    const float* __restrict__ x,       // [NT, BH*DD]
    const float* __restrict__ means,   // [BH, KK, DD]
    float* __restrict__ out_ids,       // [NT*BH]
    unsigned int* __restrict__ g_hist) // [BH*KK] pre-zeroed
{
    const int h   = blockIdx.y;
    const int tid = threadIdx.x;
    const int t0  = blockIdx.x * (TPB * TOK) + tid;   // token A
    const int t1  = t0 + TPB;                          // token B

    __shared__ float4 s_mrow[CH * (DD / 4)];  // 32 KB codebook chunk
    __shared__ float  s_m2[KK];               // 2 KB
    __shared__ unsigned int s_hist[KK];       // 2 KB

    const float4* __restrict__ mh =
        (const float4*)(means + (size_t)h * KK * DD);

    // Prologue: |m|^2 for all 512 clusters -> LDS; zero local hist
    for (int r = tid; r < KK; r += TPB) {
        const float4* row = mh + r * (DD / 4);
        float a0 = 0.f, a1 = 0.f, a2 = 0.f, a3 = 0.f;
#pragma unroll
        for (int j = 0; j < DD / 4; ++j) {
            float4 m = row[j];
            a0 = fmaf(m.x, m.x, a0);
            a1 = fmaf(m.y, m.y, a1);
            a2 = fmaf(m.z, m.z, a2);
            a3 = fmaf(m.w, m.w, a3);
        }
        s_m2[r] = (a0 + a1) + (a2 + a3);
        s_hist[r] = 0u;
    }

    // Two tokens' x into registers, pre-scaled by -2 (exact pow2).
    float4 xa[16], xb[16];
    {
        const float4* ga = (const float4*)(x + (size_t)t0 * (BH * DD) + h * DD);
        const float4* gb = (const float4*)(x + (size_t)t1 * (BH * DD) + h * DD);
#pragma unroll
        for (int j = 0; j < 16; ++j) {
            float4 v = ga[j];
            xa[j] = make_float4(-2.f * v.x, -2.f * v.y, -2.f * v.z, -2.f * v.w);
            float4 u = gb[j];
            xb[j] = make_float4(-2.f * u.x, -2.f * u.y, -2.f * u.z, -2.f * u.w);
        }
    }

    float bestA = 3.4e38f, bestB = 3.4e38f;
    int   bidA = 0,        bidB = 0;

    for (int c = 0; c < KK / CH; ++c) {
        __syncthreads();                       // protect s_mrow reuse
        const float4* src = mh + c * CH * (DD / 4);
        for (int j = tid; j < CH * (DD / 4); j += TPB) s_mrow[j] = src[j];
        __syncthreads();

        const int kbase = c * CH;
        for (int kk = 0; kk < CH; ++kk) {
            const float4* row = &s_mrow[kk * (DD / 4)];  // broadcast read
            const float m2k = s_m2[kbase + kk];
            float a0 = m2k, a1 = 0.f, a2 = 0.f, a3 = 0.f;
            float b0 = m2k, b1 = 0.f, b2 = 0.f, b3 = 0.f;
#pragma unroll
            for (int j = 0; j < 16; ++j) {
                float4 m = row[j];              // one ds_read, two tokens
                a0 = fmaf(xa[j].x, m.x, a0);
                a1 = fmaf(xa[j].y, m.y, a1);
                a2 = fmaf(xa[j].z, m.z, a2);
                a3 = fmaf(xa[j].w, m.w, a3);
                b0 = fmaf(xb[j].x, m.x, b0);
                b1 = fmaf(xb[j].y, m.y, b1);
                b2 = fmaf(xb[j].z, m.z, b2);
                b3 = fmaf(xb[j].w, m.w, b3);
            }
            float dA = (a0 + a1) + (a2 + a3);
            float dB = (b0 + b1) + (b2 + b3);
            int k = kbase + kk;
            if (dA < bestA) { bestA = dA; bidA = k; }   // strict < = first idx
            if (dB < bestB) { bestB = dB; bidB = k; }
        }
    }

    out_ids[(size_t)t0 * BH + h] = (float)bidA;   // [b,n,h] layout
    out_ids[(size_t)t1 * BH + h] = (float)bidB;

    // LDS histogram, then sparse flush to global
    atomicAdd(&s_hist[bidA], 1u);
    atomicAdd(&s_hist[bidB], 1u);
    __syncthreads();
    for (int r = tid; r < KK; r += TPB) {
        unsigned int v = s_hist[r];
        if (v) atomicAdd(&g_hist[h * KK + r], v);
    }
}

// ---------------------------------------------------------------------------
// Kernel 2: per-head exclusive prefix sum of counts -> cursor.
// grid = BH blocks, 512 threads.
// ---------------------------------------------------------------------------
__global__ __launch_bounds__(512) void vq_scan(
    const unsigned int* __restrict__ g_hist,
    unsigned int* __restrict__ cursor)
{
    const int h = blockIdx.x;
    const int tid = threadIdx.x;
    __shared__ unsigned int s[KK];

    unsigned int own = g_hist[h * KK + tid];
    s[tid] = own;
    __syncthreads();
    for (int off = 1; off < KK; off <<= 1) {
        unsigned int v = 0;
        if (tid >= off) v = s[tid - off];
        __syncthreads();
        s[tid] += v;
        __syncthreads();
    }
    cursor[h * KK + tid] = s[tid] - own;   // exclusive
}

// ---------------------------------------------------------------------------
// Kernel 3: scatter token indices into buckets. One cursor atomic per token.
// grid = (NT/256, BH), block = 256.
// ---------------------------------------------------------------------------
__global__ __launch_bounds__(256) void vq_scatter(
    const float* __restrict__ out_ids,
    unsigned int* __restrict__ cursor,
    unsigned int* __restrict__ tokbuf)   // [BH*NT]
{
    const int h = blockIdx.y;
    const int t = blockIdx.x * 256 + threadIdx.x;
    int id = (int)out_ids[(size_t)t * BH + h];
    unsigned int slot = atomicAdd(&cursor[h * KK + id], 1u);
    tokbuf[(size_t)h * NT + slot] = (unsigned int)t;
}

// ---------------------------------------------------------------------------
// Kernel 4: one BLOCK (4 waves) per (h,k) bucket. Token dim split across
// waves, 4-deep ILP per wave (16 independent chains total). lane = dim.
// Zero atomics, fused EMA. grid = BH*KK blocks of 256.
// ---------------------------------------------------------------------------
__global__ __launch_bounds__(256) void vq_gather(
    const float* __restrict__ x,
    const float* __restrict__ means,
    const unsigned int* __restrict__ g_hist,
    const unsigned int* __restrict__ cursor,   // now offset+count
    const unsigned int* __restrict__ tokbuf,
    float* __restrict__ out_means)
{
    const int w    = blockIdx.x;            // bucket id (h*KK+k)
    const int wid  = threadIdx.x >> 6;      // wave 0..3
    const int lane = threadIdx.x & 63;
    const int h    = w >> 9;

    const unsigned int cnt = g_hist[w];
    const unsigned int off = cursor[w] - cnt;
    const unsigned int* tb = tokbuf + (size_t)h * NT + off;
    const float* xb = x + h * DD + lane;

    float a0 = 0.f, a1 = 0.f, a2 = 0.f, a3 = 0.f;
    unsigned int i = wid;
    for (; i + 12 < cnt; i += 16) {          // 4 independent loads in flight
        unsigned int t0 = tb[i], t1 = tb[i + 4], t2 = tb[i + 8], t3 = tb[i + 12];
        a0 += xb[(size_t)t0 * (BH * DD)];
        a1 += xb[(size_t)t1 * (BH * DD)];
        a2 += xb[(size_t)t2 * (BH * DD)];
        a3 += xb[(size_t)t3 * (BH * DD)];
    }
    for (; i < cnt; i += 4)
        a0 += xb[(size_t)tb[i] * (BH * DD)];

    __shared__ float sp[4][DD];
    sp[wid][lane] = (a0 + a1) + (a2 + a3);
    __syncthreads();
    if (wid == 0) {
        float s = (sp[0][lane] + sp[1][lane]) + (sp[2][lane] + sp[3][lane]);
        float nm = s / (1e-6f + (float)cnt);
        float m  = means[(size_t)w * DD + lane];
        out_means[(size_t)w * DD + lane] = 0.001f * nm + 0.999f * m;
    }
}

extern "C" void kernel_launch(void* const* d_in, const int* in_sizes, int n_in,
                              void* d_out, int out_size, void* d_ws, size_t ws_size,
                              hipStream_t stream) {
    const float* x     = (const float*)d_in[0];   // [4,4096,512] f32
    const float* means = (const float*)d_in[1];   // [8,512,64]  f32

    float* out       = (float*)d_out;
    float* out_ids   = out;            // first 131072 floats
    float* out_means = out + IDS_N;    // next 262144 floats

    unsigned int* g_hist = (unsigned int*)d_ws;          // 4096
    unsigned int* cursor = g_hist + BH * KK;             // 4096
    unsigned int* tokbuf = cursor + BH * KK;             // 131072

    hipMemsetAsync(g_hist, 0, BH * KK * sizeof(unsigned int), stream);

    dim3 agrid(NT / (TPB * TOK), BH);
    vq_assign <<<agrid, dim3(TPB), 0, stream>>>(x, means, out_ids, g_hist);
    vq_scan   <<<BH, dim3(512), 0, stream>>>(g_hist, cursor);
    dim3 sgrid(NT / 256, BH);
    vq_scatter<<<sgrid, dim3(256), 0, stream>>>(out_ids, cursor, tokbuf);
    vq_gather <<<BH * KK, dim3(256), 0, stream>>>(
        x, means, g_hist, cursor, tokbuf, out_means);
}